// Round 4
// baseline (521.342 us; speedup 1.0000x reference)
//
#include <hip/hip_runtime.h>
#include <math.h>

// ---------------------------------------------------------------------------
// SimSiam head loss, 12 heads, fp32 in, B=8 H=512 W=768 -> per head (8,3,512,256)
//
// R3 structure:
//   passA: 9 raw moments of x per slice (bn1 analytic) + writes PAD4-interleaved
//          bf16 copy {c0,c1,c2,0} per position (8 B/pos). fp32 reads are
//          NON-TEMPORAL (dead after this pass -> keep L3 for the pad4 copy).
//   passB/C/D: single dense stream per wave: one uint4 load = 2 complete
//          positions. Copy-regime kernels (the 6.3 TB/s m13 pattern).
// Fallback (ws too small): R2-style fp32 3-stream kernels.
// ---------------------------------------------------------------------------

typedef unsigned short ushort_t;
typedef unsigned int uint_t;
typedef float vf4 __attribute__((ext_vector_type(4)));

constexpr int   NH      = 12;
constexpr int   POS     = 131072;               // positions per (b,head) per channel
constexpr int   NB      = 8;
constexpr long long MLL = (long long)NB * POS;  // 1,048,576 positions per slice
constexpr int   NPOSL   = NB * NH * POS;        // 12,582,912 positions per latent
constexpr float COS_EPS = 1e-8f;

constexpr int   ABLK    = 128;                  // pass A partials/slice (16x * 8b)
constexpr int   BBLK    = 512;                  // primary B/C/D partials/slice (64x * 8b)

constexpr size_t XP_USHORT  = (size_t)NPOSL * 4;    // pad4 ushorts per latent
constexpr size_t NEED_BYTES = 2 * XP_USHORT * 2 +
    ((size_t)24 * ABLK * 9 + (size_t)24 * BBLK * 6 + (size_t)24 * BBLK * 9 +
     (size_t)12 * BBLK) * 8 + 4096;

// ---------------- block reduction: 256 threads -> thread 0 ----------------
template <int K>
__device__ inline void block_reduce_to0(double (&v)[K]) {
#pragma unroll
  for (int off = 32; off > 0; off >>= 1) {
#pragma unroll
    for (int k = 0; k < K; ++k) v[k] += __shfl_down(v[k], off, 64);
  }
  __shared__ double lds[4][K];
  const int lane = threadIdx.x & 63;
  const int wv   = threadIdx.x >> 6;
  if (lane == 0) {
#pragma unroll
    for (int k = 0; k < K; ++k) lds[wv][k] = v[k];
  }
  __syncthreads();
  if (threadIdx.x == 0) {
#pragma unroll
    for (int k = 0; k < K; ++k) v[k] = lds[0][k] + lds[1][k] + lds[2][k] + lds[3][k];
  }
}

// ---------------- helpers ----------------
__device__ inline float4 ntload4(const float* p) {
  vf4 v = __builtin_nontemporal_load((const vf4*)p);
  return make_float4(v.x, v.y, v.z, v.w);
}

__device__ inline uint_t pack2bf(float lo, float hi) {   // RNE pack
  uint_t ul = __float_as_uint(lo);
  uint_t uh = __float_as_uint(hi);
  ul = ul + 0x7FFFu + ((ul >> 16) & 1u);
  uh = uh + 0x7FFFu + ((uh >> 16) & 1u);
  return (ul >> 16) | (uh & 0xFFFF0000u);
}

// decode one pad4 uint4 -> 2 positions x 3 channels
__device__ inline void dec2(const uint4 w, float (&f)[2][3]) {
  f[0][0] = __uint_as_float(w.x << 16);
  f[0][1] = __uint_as_float(w.x & 0xFFFF0000u);
  f[0][2] = __uint_as_float(w.y << 16);
  f[1][0] = __uint_as_float(w.z << 16);
  f[1][1] = __uint_as_float(w.z & 0xFFFF0000u);
  f[1][2] = __uint_as_float(w.w << 16);
}

// fallback fp32 loader: 8 consecutive positions x 3 channels
__device__ inline void load_ch3_f32(const float* __restrict__ X, size_t eoff,
                                    float (&f)[3][8]) {
#pragma unroll
  for (int c = 0; c < 3; ++c) {
    const size_t a = eoff + (size_t)c * POS;
    const float4 u0 = *(const float4*)(X + a);
    const float4 u1 = *(const float4*)(X + a + 4);
    f[c][0] = u0.x; f[c][1] = u0.y; f[c][2] = u0.z; f[c][3] = u0.w;
    f[c][4] = u1.x; f[c][5] = u1.y; f[c][6] = u1.z; f[c][7] = u1.w;
  }
}

// ---------------- pass A: raw moments of x (+ pad4 bf16 store) ----------------
template <bool STORE>
__global__ __launch_bounds__(256) void passA_kernel(
    const float* __restrict__ x1, const float* __restrict__ x2,
    ushort_t* __restrict__ xp1, ushort_t* __restrict__ xp2,
    double* __restrict__ P0) {
  const int u = blockIdx.y;        // 0..191
  const int s = u % 24;
  const int b = u / 24;
  const int n = s >> 1;
  const float* __restrict__ X = (s & 1) ? x2 : x1;
  ushort_t* __restrict__ XP = (s & 1) ? xp2 : xp1;
  const size_t eoff0 = (size_t)((b * NH + n) * 3) * POS + (size_t)blockIdx.x * 8192;
  const size_t qbase = (size_t)(b * NH + n) * POS + (size_t)blockIdx.x * 8192;

  float acc[9] = {0.f, 0.f, 0.f, 0.f, 0.f, 0.f, 0.f, 0.f, 0.f};
#pragma unroll
  for (int i = 0; i < 8; ++i) {
    const int idx = i * 1024 + threadIdx.x * 4;
    float4 v[3];
#pragma unroll
    for (int c = 0; c < 3; ++c)
      v[c] = ntload4(X + eoff0 + (size_t)c * POS + idx);
    if constexpr (STORE) {
      const float* f0 = (const float*)&v[0];
      const float* f1 = (const float*)&v[1];
      const float* f2 = (const float*)&v[2];
      uint4 A, Bu;
      A.x  = pack2bf(f0[0], f1[0]);  A.y  = pack2bf(f2[0], 0.f);
      A.z  = pack2bf(f0[1], f1[1]);  A.w  = pack2bf(f2[1], 0.f);
      Bu.x = pack2bf(f0[2], f1[2]);  Bu.y = pack2bf(f2[2], 0.f);
      Bu.z = pack2bf(f0[3], f1[3]);  Bu.w = pack2bf(f2[3], 0.f);
      uint4* dst = (uint4*)(XP + (qbase + idx) * 4);
      dst[0] = A;
      dst[1] = Bu;
    }
    const float* f0 = (const float*)&v[0];
    const float* f1 = (const float*)&v[1];
    const float* f2 = (const float*)&v[2];
#pragma unroll
    for (int j = 0; j < 4; ++j) {
      const float X0 = f0[j], X1 = f1[j], X2 = f2[j];
      acc[0] += X0;      acc[1] += X1;      acc[2] += X2;
      acc[3] += X0 * X0; acc[4] += X1 * X1; acc[5] += X2 * X2;
      acc[6] += X0 * X1; acc[7] += X0 * X2; acc[8] += X1 * X2;
    }
  }

  double v9[9];
#pragma unroll
  for (int k = 0; k < 9; ++k) v9[k] = (double)acc[k];
  block_reduce_to0<9>(v9);
  if (threadIdx.x == 0) {
    double* dst = P0 + ((size_t)s * ABLK + b * 16 + blockIdx.x) * 9;
#pragma unroll
    for (int k = 0; k < 9; ++k) dst[k] = v9[k];
  }
}

// ---------------- bn1 analytic from x moments ----------------
__global__ __launch_bounds__(256) void bn_statsA_kernel(
    const double* __restrict__ P0, const float* __restrict__ W1,
    const float* __restrict__ b1, const float* __restrict__ g1,
    const float* __restrict__ be1, float* __restrict__ derived) {
  const int s = blockIdx.x;
  const int t = threadIdx.x;
  const int n = s >> 1;
  double v[9] = {0, 0, 0, 0, 0, 0, 0, 0, 0};
  if (t < ABLK) {
    const double* p = P0 + ((size_t)s * ABLK + t) * 9;
#pragma unroll
    for (int k = 0; k < 9; ++k) v[k] = p[k];
  }
  block_reduce_to0<9>(v);
  if (t == 0) {
    const double M = (double)MLL;
    double m[3] = {v[0] / M, v[1] / M, v[2] / M};
    double C00 = v[3] / M - m[0] * m[0];
    double C11 = v[4] / M - m[1] * m[1];
    double C22 = v[5] / M - m[2] * m[2];
    double C01 = v[6] / M - m[0] * m[1];
    double C02 = v[7] / M - m[0] * m[2];
    double C12 = v[8] / M - m[1] * m[2];
    for (int o = 0; o < 3; ++o) {
      const double w0  = W1[n * 9 + o * 3 + 0];
      const double w1v = W1[n * 9 + o * 3 + 1];
      const double w2v = W1[n * 9 + o * 3 + 2];
      const double my = w0 * m[0] + w1v * m[1] + w2v * m[2] + (double)b1[n * 3 + o];
      const double vy = w0 * w0 * C00 + w1v * w1v * C11 + w2v * w2v * C22 +
                        2.0 * (w0 * w1v * C01 + w0 * w2v * C02 + w1v * w2v * C12);
      const double sc = (double)g1[n * 3 + o] / sqrt(vy + 1e-5);
      derived[s * 20 + o]     = (float)sc;
      derived[s * 20 + 3 + o] = (float)((double)be1[n * 3 + o] - my * sc);
    }
  }
}

// ---------------- primary pass B: moments of y2 (pad4 single stream) --------
__global__ __launch_bounds__(256, 4) void passBp_kernel(
    const ushort_t* __restrict__ xp1, const ushort_t* __restrict__ xp2,
    const float* __restrict__ W1, const float* __restrict__ b1,
    const float* __restrict__ W2, const float* __restrict__ b2,
    const float* __restrict__ derived, double* __restrict__ P2) {
  const int u = blockIdx.y;        // 0..191
  const int s = u % 24;
  const int b = u / 24;
  const int n = s >> 1;
  const ushort_t* __restrict__ XP = (s & 1) ? xp2 : xp1;

  float w1[3][3], bb1[3], w2[3][3], bb2[3], s1[3], t1[3];
#pragma unroll
  for (int o = 0; o < 3; ++o) {
#pragma unroll
    for (int c = 0; c < 3; ++c) {
      w1[o][c] = W1[n * 9 + o * 3 + c];
      w2[o][c] = W2[n * 9 + o * 3 + c];
    }
    bb1[o] = b1[n * 3 + o];
    bb2[o] = b2[n * 3 + o];
    s1[o]  = derived[s * 20 + o];
    t1[o]  = derived[s * 20 + 3 + o];
  }

  const uint4* __restrict__ U = (const uint4*)XP +
      (((size_t)(b * NH + n) * POS) >> 1) + (size_t)blockIdx.x * 1024;
  uint4 r[4];
#pragma unroll
  for (int i = 0; i < 4; ++i) r[i] = U[i * 256 + threadIdx.x];

  float acc[6] = {0.f, 0.f, 0.f, 0.f, 0.f, 0.f};
#pragma unroll
  for (int i = 0; i < 4; ++i) {
    float f[2][3];
    dec2(r[i], f);
#pragma unroll
    for (int j = 0; j < 2; ++j) {
      const float X0 = f[j][0], X1 = f[j][1], X2 = f[j][2];
      float a[3];
#pragma unroll
      for (int o = 0; o < 3; ++o) {
        const float y = fmaf(w1[o][0], X0, fmaf(w1[o][1], X1, fmaf(w1[o][2], X2, bb1[o])));
        a[o] = fmaxf(0.f, fmaf(s1[o], y, t1[o]));
      }
#pragma unroll
      for (int o = 0; o < 3; ++o) {
        const float y2v = fmaf(w2[o][0], a[0], fmaf(w2[o][1], a[1], fmaf(w2[o][2], a[2], bb2[o])));
        acc[o]     += y2v;
        acc[3 + o] += y2v * y2v;
      }
    }
  }

  double v[6];
#pragma unroll
  for (int k = 0; k < 6; ++k) v[k] = (double)acc[k];
  block_reduce_to0<6>(v);
  if (threadIdx.x == 0) {
    double* dst = P2 + ((size_t)s * BBLK + b * 64 + blockIdx.x) * 6;
#pragma unroll
    for (int k = 0; k < 6; ++k) dst[k] = v[k];
  }
}

// ---------------- bn2 stats ----------------
__global__ __launch_bounds__(256) void bn_statsB_kernel(
    const double* __restrict__ P2, const float* __restrict__ gamma,
    const float* __restrict__ beta, float* __restrict__ derived, int cnt) {
  const int s = blockIdx.x;
  const int t = threadIdx.x;
  const int n = s >> 1;
  double v[6] = {0, 0, 0, 0, 0, 0};
  for (int k = t; k < cnt; k += 256) {
    const double* p = P2 + ((size_t)s * BBLK + k) * 6;
#pragma unroll
    for (int q = 0; q < 6; ++q) v[q] += p[q];
  }
  block_reduce_to0<6>(v);
  if (t == 0) {
#pragma unroll
    for (int c = 0; c < 3; ++c) {
      const double mean = v[c] / (double)MLL;
      const double var  = v[3 + c] / (double)MLL - mean * mean;
      const double sc   = (double)gamma[n * 3 + c] / sqrt(var + 1e-5);
      derived[s * 20 + 6 + c] = (float)sc;
      derived[s * 20 + 9 + c] = (float)((double)beta[n * 3 + c] - mean * sc);
    }
  }
}

// ---------------- primary pass C: y3 full 2nd moments (pad4) ----------------
__global__ __launch_bounds__(256, 4) void passCp_kernel(
    const ushort_t* __restrict__ xp1, const ushort_t* __restrict__ xp2,
    const float* __restrict__ W1, const float* __restrict__ b1,
    const float* __restrict__ W2, const float* __restrict__ b2,
    const float* __restrict__ W3, const float* __restrict__ b3,
    const float* __restrict__ derived, double* __restrict__ P3) {
  const int u = blockIdx.y;
  const int s = u % 24;
  const int b = u / 24;
  const int n = s >> 1;
  const ushort_t* __restrict__ XP = (s & 1) ? xp2 : xp1;

  float w1[3][3], bb1[3], w2[3][3], bb2[3], w3[3][3], bb3[3];
  float s1[3], t1[3], s2[3], t2[3];
#pragma unroll
  for (int o = 0; o < 3; ++o) {
#pragma unroll
    for (int c = 0; c < 3; ++c) {
      w1[o][c] = W1[n * 9 + o * 3 + c];
      w2[o][c] = W2[n * 9 + o * 3 + c];
      w3[o][c] = W3[n * 9 + o * 3 + c];
    }
    bb1[o] = b1[n * 3 + o];
    bb2[o] = b2[n * 3 + o];
    bb3[o] = b3[n * 3 + o];
    s1[o]  = derived[s * 20 + o];
    t1[o]  = derived[s * 20 + 3 + o];
    s2[o]  = derived[s * 20 + 6 + o];
    t2[o]  = derived[s * 20 + 9 + o];
  }

  const uint4* __restrict__ U = (const uint4*)XP +
      (((size_t)(b * NH + n) * POS) >> 1) + (size_t)blockIdx.x * 1024;
  uint4 r[4];
#pragma unroll
  for (int i = 0; i < 4; ++i) r[i] = U[i * 256 + threadIdx.x];

  float acc[9] = {0.f, 0.f, 0.f, 0.f, 0.f, 0.f, 0.f, 0.f, 0.f};
#pragma unroll
  for (int i = 0; i < 4; ++i) {
    float f[2][3];
    dec2(r[i], f);
#pragma unroll
    for (int j = 0; j < 2; ++j) {
      const float X0 = f[j][0], X1 = f[j][1], X2 = f[j][2];
      float a[3], a2[3], y3[3];
#pragma unroll
      for (int o = 0; o < 3; ++o) {
        const float y = fmaf(w1[o][0], X0, fmaf(w1[o][1], X1, fmaf(w1[o][2], X2, bb1[o])));
        a[o] = fmaxf(0.f, fmaf(s1[o], y, t1[o]));
      }
#pragma unroll
      for (int o = 0; o < 3; ++o) {
        const float y = fmaf(w2[o][0], a[0], fmaf(w2[o][1], a[1], fmaf(w2[o][2], a[2], bb2[o])));
        a2[o] = fmaxf(0.f, fmaf(s2[o], y, t2[o]));
      }
#pragma unroll
      for (int o = 0; o < 3; ++o) {
        y3[o] = fmaf(w3[o][0], a2[0], fmaf(w3[o][1], a2[1], fmaf(w3[o][2], a2[2], bb3[o])));
        acc[o]     += y3[o];
        acc[3 + o] += y3[o] * y3[o];
      }
      acc[6] += y3[0] * y3[1];
      acc[7] += y3[0] * y3[2];
      acc[8] += y3[1] * y3[2];
    }
  }

  double v[9];
#pragma unroll
  for (int k = 0; k < 9; ++k) v[k] = (double)acc[k];
  block_reduce_to0<9>(v);
  if (threadIdx.x == 0) {
    double* dst = P3 + ((size_t)s * BBLK + b * 64 + blockIdx.x) * 9;
#pragma unroll
    for (int k = 0; k < 9; ++k) dst[k] = v[k];
  }
}

// ---------------- bn3 + bn4 stats ----------------
__global__ __launch_bounds__(256) void bn_statsC_kernel(
    const double* __restrict__ P3, const float* __restrict__ g3,
    const float* __restrict__ be3, const float* __restrict__ W4,
    const float* __restrict__ b4, const float* __restrict__ g4,
    const float* __restrict__ be4, float* __restrict__ derived, int cnt) {
  const int s = blockIdx.x;
  const int t = threadIdx.x;
  const int n = s >> 1;
  double v[9] = {0, 0, 0, 0, 0, 0, 0, 0, 0};
  for (int k = t; k < cnt; k += 256) {
    const double* p = P3 + ((size_t)s * BBLK + k) * 9;
#pragma unroll
    for (int q = 0; q < 9; ++q) v[q] += p[q];
  }
  block_reduce_to0<9>(v);
  if (t == 0) {
    const double M = (double)MLL;
    double mean[3] = {v[0] / M, v[1] / M, v[2] / M};
    double cov[3][3];
    cov[0][0] = v[3] / M - mean[0] * mean[0];
    cov[1][1] = v[4] / M - mean[1] * mean[1];
    cov[2][2] = v[5] / M - mean[2] * mean[2];
    cov[0][1] = cov[1][0] = v[6] / M - mean[0] * mean[1];
    cov[0][2] = cov[2][0] = v[7] / M - mean[0] * mean[2];
    cov[1][2] = cov[2][1] = v[8] / M - mean[1] * mean[2];

    double s3[3], t3[3];
    for (int c = 0; c < 3; ++c) {
      s3[c] = (double)g3[n * 3 + c] / sqrt(cov[c][c] + 1e-5);
      t3[c] = (double)be3[n * 3 + c] - mean[c] * s3[c];
      derived[s * 20 + 12 + c] = (float)s3[c];
      derived[s * 20 + 15 + c] = (float)t3[c];
    }
    double uu[3], dd = (double)b4[n];
    for (int c = 0; c < 3; ++c) {
      uu[c] = (double)W4[n * 3 + c] * s3[c];
      dd += (double)W4[n * 3 + c] * t3[c];
    }
    double m4 = dd;
    for (int c = 0; c < 3; ++c) m4 += uu[c] * mean[c];
    double v4 = 0.0;
    for (int i = 0; i < 3; ++i)
      for (int j = 0; j < 3; ++j) v4 += uu[i] * uu[j] * cov[i][j];
    const double s4 = (double)g4[n] / sqrt(v4 + 1e-5);
    derived[s * 20 + 18] = (float)s4;
    derived[s * 20 + 19] = (float)((double)be4[n] - m4 * s4);
  }
}

// ---------------- fused per-position forward chain ----------------
__device__ inline void fwd_chain(
    const float w1[3][3], const float bb1[3],
    const float w2[3][3], const float bb2[3],
    const float w3[3][3], const float bb3[3],
    const float w4[3], float b4s, const float w5[3], const float b5v[3],
    const float* S, float X0, float X1, float X2, float z[3], float p[3]) {
  float a[3], a2[3];
#pragma unroll
  for (int o = 0; o < 3; ++o) {
    const float y = fmaf(w1[o][0], X0, fmaf(w1[o][1], X1, fmaf(w1[o][2], X2, bb1[o])));
    a[o] = fmaxf(0.f, fmaf(S[o], y, S[3 + o]));
  }
#pragma unroll
  for (int o = 0; o < 3; ++o) {
    const float y = fmaf(w2[o][0], a[0], fmaf(w2[o][1], a[1], fmaf(w2[o][2], a[2], bb2[o])));
    a2[o] = fmaxf(0.f, fmaf(S[6 + o], y, S[9 + o]));
  }
  float y4 = b4s;
#pragma unroll
  for (int o = 0; o < 3; ++o) {
    const float y = fmaf(w3[o][0], a2[0], fmaf(w3[o][1], a2[1], fmaf(w3[o][2], a2[2], bb3[o])));
    z[o] = fmaf(S[12 + o], y, S[15 + o]);
    y4 = fmaf(w4[o], z[o], y4);
  }
  const float h = fmaxf(0.f, fmaf(S[18], y4, S[19]));
#pragma unroll
  for (int o = 0; o < 3; ++o) p[o] = fmaf(w5[o], h, b5v[o]);
}

// ---------------- cosine accumulate for 2 decoded positions ----------------
__device__ inline void cos_acc2(
    const float w1[3][3], const float bb1[3], const float w2[3][3],
    const float bb2[3], const float w3[3][3], const float bb3[3],
    const float w4[3], float b4s, const float w5[3], const float b5v[3],
    const float* S0, const float* S1,
    const float (&fA)[2][3], const float (&fB)[2][3], float& acc) {
#pragma unroll
  for (int j = 0; j < 2; ++j) {
    float z1[3], p1[3], z2[3], p2[3];
    fwd_chain(w1, bb1, w2, bb2, w3, bb3, w4, b4s, w5, b5v, S0,
              fA[j][0], fA[j][1], fA[j][2], z1, p1);
    fwd_chain(w1, bb1, w2, bb2, w3, bb3, w4, b4s, w5, b5v, S1,
              fB[j][0], fB[j][1], fB[j][2], z2, p2);

    const float d12 = p1[0] * z2[0] + p1[1] * z2[1] + p1[2] * z2[2];
    const float pp1 = p1[0] * p1[0] + p1[1] * p1[1] + p1[2] * p1[2];
    const float zz2 = z2[0] * z2[0] + z2[1] * z2[1] + z2[2] * z2[2];
    const float c12 = d12 / (fmaxf(sqrtf(pp1), COS_EPS) * fmaxf(sqrtf(zz2), COS_EPS));

    const float d21 = p2[0] * z1[0] + p2[1] * z1[1] + p2[2] * z1[2];
    const float pp2 = p2[0] * p2[0] + p2[1] * p2[1] + p2[2] * p2[2];
    const float zz1 = z1[0] * z1[0] + z1[1] * z1[1] + z1[2] * z1[2];
    const float c21 = d21 / (fmaxf(sqrtf(pp2), COS_EPS) * fmaxf(sqrtf(zz1), COS_EPS));

    acc += c12 + c21;
  }
}

// ---------------- primary pass D: cosine loss (pad4) ----------------
__global__ __launch_bounds__(256, 4) void passDp_kernel(
    const ushort_t* __restrict__ xp1, const ushort_t* __restrict__ xp2,
    const float* __restrict__ W1, const float* __restrict__ b1,
    const float* __restrict__ W2, const float* __restrict__ b2,
    const float* __restrict__ W3, const float* __restrict__ b3,
    const float* __restrict__ W4, const float* __restrict__ b4,
    const float* __restrict__ W5, const float* __restrict__ b5,
    const float* __restrict__ derived, double* __restrict__ PL) {
  const int u = blockIdx.y;        // 0..95
  const int n = u % 12;
  const int b = u / 12;

  float w1[3][3], bb1[3], w2[3][3], bb2[3], w3[3][3], bb3[3];
  float w4[3], b4s, w5[3], b5v[3];
#pragma unroll
  for (int o = 0; o < 3; ++o) {
#pragma unroll
    for (int c = 0; c < 3; ++c) {
      w1[o][c] = W1[n * 9 + o * 3 + c];
      w2[o][c] = W2[n * 9 + o * 3 + c];
      w3[o][c] = W3[n * 9 + o * 3 + c];
    }
    bb1[o] = b1[n * 3 + o];
    bb2[o] = b2[n * 3 + o];
    bb3[o] = b3[n * 3 + o];
    w4[o]  = W4[n * 3 + o];
    w5[o]  = W5[n * 3 + o];
    b5v[o] = b5[n * 3 + o];
  }
  b4s = b4[n];

  float S0[20], S1[20];
#pragma unroll
  for (int k = 0; k < 20; ++k) {
    S0[k] = derived[(n * 2 + 0) * 20 + k];
    S1[k] = derived[(n * 2 + 1) * 20 + k];
  }

  const size_t R = (((size_t)(b * NH + n) * POS) >> 1) + (size_t)blockIdx.x * 1024;
  const uint4* __restrict__ U1 = (const uint4*)xp1 + R;
  const uint4* __restrict__ U2 = (const uint4*)xp2 + R;

  float acc = 0.f;
#pragma unroll
  for (int i = 0; i < 4; ++i) {
    const uint4 rA = U1[i * 256 + threadIdx.x];
    const uint4 rB = U2[i * 256 + threadIdx.x];
    float fA[2][3], fB[2][3];
    dec2(rA, fA);
    dec2(rB, fB);
    cos_acc2(w1, bb1, w2, bb2, w3, bb3, w4, b4s, w5, b5v, S0, S1, fA, fB, acc);
  }

  double v[1] = {(double)acc};
  block_reduce_to0<1>(v);
  if (threadIdx.x == 0) PL[(size_t)n * BBLK + b * 64 + blockIdx.x] = v[0];
}

// ---------------- fallback fp32 passes (3-stream, read original x) ----------
__global__ __launch_bounds__(256) void passBf_kernel(
    const float* __restrict__ x1, const float* __restrict__ x2,
    const float* __restrict__ W1, const float* __restrict__ b1,
    const float* __restrict__ W2, const float* __restrict__ b2,
    const float* __restrict__ derived, double* __restrict__ P2) {
  const int u = blockIdx.y;
  const int s = u % 24;
  const int b = u / 24;
  const int n = s >> 1;
  const float* __restrict__ X = (s & 1) ? x2 : x1;
  const size_t off0 = (size_t)((b * NH + n) * 3) * POS + (size_t)blockIdx.x * 8192;

  float w1[3][3], bb1[3], w2[3][3], bb2[3], s1[3], t1[3];
#pragma unroll
  for (int o = 0; o < 3; ++o) {
#pragma unroll
    for (int c = 0; c < 3; ++c) {
      w1[o][c] = W1[n * 9 + o * 3 + c];
      w2[o][c] = W2[n * 9 + o * 3 + c];
    }
    bb1[o] = b1[n * 3 + o];
    bb2[o] = b2[n * 3 + o];
    s1[o]  = derived[s * 20 + o];
    t1[o]  = derived[s * 20 + 3 + o];
  }

  float acc[6] = {0.f, 0.f, 0.f, 0.f, 0.f, 0.f};
  for (int i = 0; i < 4; ++i) {
    float f[3][8];
    load_ch3_f32(X, off0 + i * 2048 + threadIdx.x * 8, f);
#pragma unroll
    for (int j = 0; j < 8; ++j) {
      const float X0 = f[0][j], X1 = f[1][j], X2 = f[2][j];
      float a[3];
#pragma unroll
      for (int o = 0; o < 3; ++o) {
        const float y = fmaf(w1[o][0], X0, fmaf(w1[o][1], X1, fmaf(w1[o][2], X2, bb1[o])));
        a[o] = fmaxf(0.f, fmaf(s1[o], y, t1[o]));
      }
#pragma unroll
      for (int o = 0; o < 3; ++o) {
        const float y2v = fmaf(w2[o][0], a[0], fmaf(w2[o][1], a[1], fmaf(w2[o][2], a[2], bb2[o])));
        acc[o]     += y2v;
        acc[3 + o] += y2v * y2v;
      }
    }
  }

  double v[6];
#pragma unroll
  for (int k = 0; k < 6; ++k) v[k] = (double)acc[k];
  block_reduce_to0<6>(v);
  if (threadIdx.x == 0) {
    double* dst = P2 + ((size_t)s * BBLK + b * 16 + blockIdx.x) * 6;
#pragma unroll
    for (int k = 0; k < 6; ++k) dst[k] = v[k];
  }
}

__global__ __launch_bounds__(256) void passCf_kernel(
    const float* __restrict__ x1, const float* __restrict__ x2,
    const float* __restrict__ W1, const float* __restrict__ b1,
    const float* __restrict__ W2, const float* __restrict__ b2,
    const float* __restrict__ W3, const float* __restrict__ b3,
    const float* __restrict__ derived, double* __restrict__ P3) {
  const int u = blockIdx.y;
  const int s = u % 24;
  const int b = u / 24;
  const int n = s >> 1;
  const float* __restrict__ X = (s & 1) ? x2 : x1;
  const size_t off0 = (size_t)((b * NH + n) * 3) * POS + (size_t)blockIdx.x * 8192;

  float w1[3][3], bb1[3], w2[3][3], bb2[3], w3[3][3], bb3[3];
  float s1[3], t1[3], s2[3], t2[3];
#pragma unroll
  for (int o = 0; o < 3; ++o) {
#pragma unroll
    for (int c = 0; c < 3; ++c) {
      w1[o][c] = W1[n * 9 + o * 3 + c];
      w2[o][c] = W2[n * 9 + o * 3 + c];
      w3[o][c] = W3[n * 9 + o * 3 + c];
    }
    bb1[o] = b1[n * 3 + o];
    bb2[o] = b2[n * 3 + o];
    bb3[o] = b3[n * 3 + o];
    s1[o]  = derived[s * 20 + o];
    t1[o]  = derived[s * 20 + 3 + o];
    s2[o]  = derived[s * 20 + 6 + o];
    t2[o]  = derived[s * 20 + 9 + o];
  }

  float acc[9] = {0.f, 0.f, 0.f, 0.f, 0.f, 0.f, 0.f, 0.f, 0.f};
  for (int i = 0; i < 4; ++i) {
    float f[3][8];
    load_ch3_f32(X, off0 + i * 2048 + threadIdx.x * 8, f);
#pragma unroll
    for (int j = 0; j < 8; ++j) {
      const float X0 = f[0][j], X1 = f[1][j], X2 = f[2][j];
      float a[3], a2[3], y3[3];
#pragma unroll
      for (int o = 0; o < 3; ++o) {
        const float y = fmaf(w1[o][0], X0, fmaf(w1[o][1], X1, fmaf(w1[o][2], X2, bb1[o])));
        a[o] = fmaxf(0.f, fmaf(s1[o], y, t1[o]));
      }
#pragma unroll
      for (int o = 0; o < 3; ++o) {
        const float y = fmaf(w2[o][0], a[0], fmaf(w2[o][1], a[1], fmaf(w2[o][2], a[2], bb2[o])));
        a2[o] = fmaxf(0.f, fmaf(s2[o], y, t2[o]));
      }
#pragma unroll
      for (int o = 0; o < 3; ++o) {
        y3[o] = fmaf(w3[o][0], a2[0], fmaf(w3[o][1], a2[1], fmaf(w3[o][2], a2[2], bb3[o])));
        acc[o]     += y3[o];
        acc[3 + o] += y3[o] * y3[o];
      }
      acc[6] += y3[0] * y3[1];
      acc[7] += y3[0] * y3[2];
      acc[8] += y3[1] * y3[2];
    }
  }

  double v[9];
#pragma unroll
  for (int k = 0; k < 9; ++k) v[k] = (double)acc[k];
  block_reduce_to0<9>(v);
  if (threadIdx.x == 0) {
    double* dst = P3 + ((size_t)s * BBLK + b * 16 + blockIdx.x) * 9;
#pragma unroll
    for (int k = 0; k < 9; ++k) dst[k] = v[k];
  }
}

__global__ __launch_bounds__(256) void passDf_kernel(
    const float* __restrict__ x1, const float* __restrict__ x2,
    const float* __restrict__ W1, const float* __restrict__ b1,
    const float* __restrict__ W2, const float* __restrict__ b2,
    const float* __restrict__ W3, const float* __restrict__ b3,
    const float* __restrict__ W4, const float* __restrict__ b4,
    const float* __restrict__ W5, const float* __restrict__ b5,
    const float* __restrict__ derived, double* __restrict__ PL) {
  const int u = blockIdx.y;        // 0..95
  const int n = u % 12;
  const int b = u / 12;
  const size_t off0 = (size_t)((b * NH + n) * 3) * POS + (size_t)blockIdx.x * 8192;

  float w1[3][3], bb1[3], w2[3][3], bb2[3], w3[3][3], bb3[3];
  float w4[3], b4s, w5[3], b5v[3];
#pragma unroll
  for (int o = 0; o < 3; ++o) {
#pragma unroll
    for (int c = 0; c < 3; ++c) {
      w1[o][c] = W1[n * 9 + o * 3 + c];
      w2[o][c] = W2[n * 9 + o * 3 + c];
      w3[o][c] = W3[n * 9 + o * 3 + c];
    }
    bb1[o] = b1[n * 3 + o];
    bb2[o] = b2[n * 3 + o];
    bb3[o] = b3[n * 3 + o];
    w4[o]  = W4[n * 3 + o];
    w5[o]  = W5[n * 3 + o];
    b5v[o] = b5[n * 3 + o];
  }
  b4s = b4[n];

  float S0[20], S1[20];
#pragma unroll
  for (int k = 0; k < 20; ++k) {
    S0[k] = derived[(n * 2 + 0) * 20 + k];
    S1[k] = derived[(n * 2 + 1) * 20 + k];
  }

  float acc = 0.f;
  for (int i = 0; i < 4; ++i) {
    const size_t eoff = off0 + i * 2048 + threadIdx.x * 8;
    float fA[3][8], fB[3][8];
    load_ch3_f32(x1, eoff, fA);
    load_ch3_f32(x2, eoff, fB);
#pragma unroll
    for (int j = 0; j < 8; ++j) {
      float z1[3], p1[3], z2[3], p2[3];
      fwd_chain(w1, bb1, w2, bb2, w3, bb3, w4, b4s, w5, b5v, S0,
                fA[0][j], fA[1][j], fA[2][j], z1, p1);
      fwd_chain(w1, bb1, w2, bb2, w3, bb3, w4, b4s, w5, b5v, S1,
                fB[0][j], fB[1][j], fB[2][j], z2, p2);

      const float d12 = p1[0] * z2[0] + p1[1] * z2[1] + p1[2] * z2[2];
      const float pp1 = p1[0] * p1[0] + p1[1] * p1[1] + p1[2] * p1[2];
      const float zz2 = z2[0] * z2[0] + z2[1] * z2[1] + z2[2] * z2[2];
      const float c12 = d12 / (fmaxf(sqrtf(pp1), COS_EPS) * fmaxf(sqrtf(zz2), COS_EPS));

      const float d21 = p2[0] * z1[0] + p2[1] * z1[1] + p2[2] * z1[2];
      const float pp2 = p2[0] * p2[0] + p2[1] * p2[1] + p2[2] * p2[2];
      const float zz1 = z1[0] * z1[0] + z1[1] * z1[1] + z1[2] * z1[2];
      const float c21 = d21 / (fmaxf(sqrtf(pp2), COS_EPS) * fmaxf(sqrtf(zz1), COS_EPS));

      acc += c12 + c21;
    }
  }

  double v[1] = {(double)acc};
  block_reduce_to0<1>(v);
  if (threadIdx.x == 0) PL[(size_t)n * BBLK + b * 16 + blockIdx.x] = v[0];
}

// ---------------- finalize ----------------
__global__ __launch_bounds__(256) void finalize_kernel(
    const double* __restrict__ PL, float* __restrict__ out, int cntPerN) {
  double v[1] = {0.0};
  for (int n = 0; n < 12; ++n)
    for (int k = threadIdx.x; k < cntPerN; k += 256)
      v[0] += PL[(size_t)n * BBLK + k];
  block_reduce_to0<1>(v);
  if (threadIdx.x == 0) out[0] = (float)(-0.5 * v[0] / (double)MLL);
}

// ---------------- launch ----------------
extern "C" void kernel_launch(void* const* d_in, const int* in_sizes, int n_in,
                              void* d_out, int out_size, void* d_ws, size_t ws_size,
                              hipStream_t stream) {
  const float* x1  = (const float*)d_in[0];
  const float* x2  = (const float*)d_in[1];
  const float* W1  = (const float*)d_in[2];
  const float* b1  = (const float*)d_in[3];
  const float* g1  = (const float*)d_in[4];
  const float* be1 = (const float*)d_in[5];
  const float* W2  = (const float*)d_in[6];
  const float* b2  = (const float*)d_in[7];
  const float* g2  = (const float*)d_in[8];
  const float* be2 = (const float*)d_in[9];
  const float* W3  = (const float*)d_in[10];
  const float* b3  = (const float*)d_in[11];
  const float* g3  = (const float*)d_in[12];
  const float* be3 = (const float*)d_in[13];
  const float* W4  = (const float*)d_in[14];
  const float* b4  = (const float*)d_in[15];
  const float* g4  = (const float*)d_in[16];
  const float* be4 = (const float*)d_in[17];
  const float* W5  = (const float*)d_in[18];
  const float* b5  = (const float*)d_in[19];

  const bool big = ws_size >= NEED_BYTES;
  ushort_t* xp1 = nullptr;
  ushort_t* xp2 = nullptr;
  double* dbase;
  if (big) {
    xp1 = (ushort_t*)d_ws;
    xp2 = xp1 + XP_USHORT;
    dbase = (double*)(xp2 + XP_USHORT);
  } else {
    dbase = (double*)d_ws;
  }
  double* P0 = dbase;
  double* P2 = P0 + (size_t)24 * ABLK * 9;
  double* P3 = P2 + (size_t)24 * BBLK * 6;
  double* PL = P3 + (size_t)24 * BBLK * 9;
  float* derived = (float*)(PL + 12 * BBLK);

  const dim3 blk(256);
  const dim3 gA(16, 192);

  if (big) {
    passA_kernel<true><<<gA, blk, 0, stream>>>(x1, x2, xp1, xp2, P0);
    bn_statsA_kernel<<<24, blk, 0, stream>>>(P0, W1, b1, g1, be1, derived);
    passBp_kernel<<<dim3(64, 192), blk, 0, stream>>>(xp1, xp2, W1, b1, W2, b2,
                                                     derived, P2);
    bn_statsB_kernel<<<24, blk, 0, stream>>>(P2, g2, be2, derived, BBLK);
    passCp_kernel<<<dim3(64, 192), blk, 0, stream>>>(xp1, xp2, W1, b1, W2, b2,
                                                     W3, b3, derived, P3);
    bn_statsC_kernel<<<24, blk, 0, stream>>>(P3, g3, be3, W4, b4, g4, be4,
                                             derived, BBLK);
    passDp_kernel<<<dim3(64, 96), blk, 0, stream>>>(xp1, xp2, W1, b1, W2, b2,
                                                    W3, b3, W4, b4, W5, b5,
                                                    derived, PL);
    finalize_kernel<<<1, blk, 0, stream>>>(PL, (float*)d_out, BBLK);
  } else {
    passA_kernel<false><<<gA, blk, 0, stream>>>(x1, x2, nullptr, nullptr, P0);
    bn_statsA_kernel<<<24, blk, 0, stream>>>(P0, W1, b1, g1, be1, derived);
    passBf_kernel<<<gA, blk, 0, stream>>>(x1, x2, W1, b1, W2, b2, derived, P2);
    bn_statsB_kernel<<<24, blk, 0, stream>>>(P2, g2, be2, derived, ABLK);
    passCf_kernel<<<gA, blk, 0, stream>>>(x1, x2, W1, b1, W2, b2, W3, b3,
                                          derived, P3);
    bn_statsC_kernel<<<24, blk, 0, stream>>>(P3, g3, be3, W4, b4, g4, be4,
                                             derived, ABLK);
    passDf_kernel<<<dim3(16, 96), blk, 0, stream>>>(x1, x2, W1, b1, W2, b2,
                                                    W3, b3, W4, b4, W5, b5,
                                                    derived, PL);
    finalize_kernel<<<1, blk, 0, stream>>>(PL, (float*)d_out, ABLK);
  }
}